// Round 2
// baseline (281.121 us; speedup 1.0000x reference)
//
#include <hip/hip_runtime.h>
#include <hip/hip_bf16.h>

typedef __hip_bfloat16 bf16;

__device__ __forceinline__ float bf2f(bf16 h) { return __bfloat162float(h); }
__device__ __forceinline__ bf16 us2bf(unsigned short u) {
  union { unsigned short s; bf16 h; } v; v.s = u; return v.h;
}

#define HH 128
#define WW 128
#define HS 512
#define WSZ 512
#define NC 64
#define QN (HS*WSZ)
#define TILE 16

// ---- ws float-offset layout (total ~7.67 MB) ----
#define O_INP    0        // 49152
#define O_ENCW   49152    // 1728
#define O_ENCB   50880    // 64
#define O_W1     50944    // 256
#define O_B1     51200    // 64
#define O_W2     51264    // 4096
#define O_B2     55360    // 64
#define O_RW     55424    // 256
#define O_RB     55680    // 4
#define O_OW     55684    // 128
#define O_OB     55812    // 2
#define O_TW     55814    // 1728
#define O_TB     57542    // 3
#define O_WC     57545    // 2048
#define O_WE     59593    // 2048  (end 61641)
#define O_OFFTAB 61696    // 32
#define O_RTAB   61728    // 64   (end 61792)
#define O_FLAG   61792    // 1
#define O_CWC    61824    // 16*512 = 8192
#define O_CWE    70016    // 8192 (end 78208)
#define O_FEAT   81920    // 64*16384 = 1048576 (end 1130496)
#define O_PRED   1130496  // 3*262144 = 786432 (end 1916928 floats = 7.67 MB)

// sorted-by-class halo decode tables (18x18 halo, classes by ((p+3)&3))
__constant__ int PREF[16] = {0,25,45,65,90,110,126,142,162,182,198,214,234,259,279,299};

// generic input read honoring dtype flag
__device__ __forceinline__ float rdin(const void* p, int i, bool f32m) {
  return f32m ? ((const float*)p)[i] : bf2f(((const bf16*)p)[i]);
}

// ---- 0. dtype sniff: bf16 vs f32 inputs ----
__global__ void k_sniff(const void* __restrict__ inp, float* __restrict__ ws) {
  int o = threadIdx.x;  // 0..63
  unsigned short u = ((const unsigned short*)inp)[2*o];  // valid read in both modes
  float v = bf2f(us2bf(u));
  // true-bf16 N(0,1) sample: finite, |v|<64, not absurdly tiny
  bool bf_ok = (v == v) && (fabsf(v) < 64.0f) && (fabsf(v) < 1e30f);
  unsigned long long m = __ballot(bf_ok);
  if (o == 0) ws[O_FLAG] = (__popcll(m) >= 48) ? 0.0f : 1.0f;  // 1.0 => f32 inputs
}

// ---- 1. convert inputs/weights to f32 in ws ----
__global__ __launch_bounds__(256) void k_convert(
    const void* __restrict__ inp, const void* __restrict__ encw, const void* __restrict__ encb,
    const void* __restrict__ w1, const void* __restrict__ b1,
    const void* __restrict__ w2, const void* __restrict__ b2,
    const void* __restrict__ rw, const void* __restrict__ rb,
    const void* __restrict__ ow, const void* __restrict__ ob,
    const void* __restrict__ tw, const void* __restrict__ tb,
    const void* __restrict__ wc, const void* __restrict__ we,
    float* __restrict__ ws) {
  bool f32m = ws[O_FLAG] > 0.5f;
  int i = blockIdx.x*256 + threadIdx.x;
  if (i < 49152) ws[O_INP + i] = rdin(inp, i, f32m);
  if (i < 1728) { ws[O_ENCW + i] = rdin(encw, i, f32m); ws[O_TW + i] = rdin(tw, i, f32m); }
  if (i < 64)   { ws[O_ENCB+i] = rdin(encb,i,f32m); ws[O_B1+i] = rdin(b1,i,f32m); ws[O_B2+i] = rdin(b2,i,f32m); }
  if (i < 256)  { ws[O_W1+i] = rdin(w1,i,f32m); ws[O_RW+i] = rdin(rw,i,f32m); }
  if (i < 4096) ws[O_W2+i] = rdin(w2,i,f32m);
  if (i < 4)    ws[O_RB+i] = rdin(rb,i,f32m);
  if (i < 128)  ws[O_OW+i] = rdin(ow,i,f32m);
  if (i < 2)    ws[O_OB+i] = rdin(ob,i,f32m);
  if (i < 3)    ws[O_TB+i] = rdin(tb,i,f32m);
  if (i < 2048) { ws[O_WC+i] = rdin(wc,i,f32m); ws[O_WE+i] = rdin(we,i,f32m); }
}

// ---- 2. the 16 (y%4,x%4) classes: body MLP -> off(2), r(4) ----
__global__ __launch_bounds__(64) void k_class(float* __restrict__ ws) {
  __shared__ float sh1[64];
  __shared__ float sh2[64];
  int cls = blockIdx.x;          // 0..15
  int o = threadIdx.x;           // 0..63
  float m = (float)(cls >> 2), n = (float)(cls & 3);
  float ch = (m + 0.5f)*0.25f - 0.5f;
  float cw = (n + 0.5f)*0.25f - 0.5f;
  const float* W1 = ws + O_W1; const float* B1 = ws + O_B1;
  const float* W2 = ws + O_W2; const float* B2 = ws + O_B2;
  float s = W1[o*4+0]*0.25f + W1[o*4+1]*0.25f + W1[o*4+2]*ch + W1[o*4+3]*cw + B1[o];
  sh1[o] = fmaxf(s, 0.0f);
  __syncthreads();
  float s2 = B2[o];
  for (int i = 0; i < 64; i++) s2 = fmaf(W2[o*64+i], sh1[i], s2);
  sh2[o] = fmaxf(s2, 0.0f);
  __syncthreads();
  if (o < 2) {
    const float* OW = ws + O_OW;
    float a = ws[O_OB + o];
    for (int i = 0; i < 64; i++) a = fmaf(OW[o*64+i], sh2[i], a);
    ws[O_OFFTAB + cls*2 + o] = a;
  } else if (o < 6) {
    int e = o - 2;
    const float* RW = ws + O_RW;
    float a = ws[O_RB + e];
    for (int i = 0; i < 64; i++) a = fmaf(RW[e*64+i], sh2[i], a);
    ws[O_RTAB + cls*4 + e] = 1.0f / (1.0f + expf(-a));
  }
}

// ---- 3. fold routing weights into per-class combined expert weights ----
// cwc[cls][c][k] = sum_e r[cls][e] * WC[e][k][c]   (k contiguous for vector loads)
// cwe[cls][c][k] = sum_e r[cls][e] * WE[e][c][k]
__global__ __launch_bounds__(256) void k_combine(float* __restrict__ ws) {
  int cls = blockIdx.x;
  float r0 = ws[O_RTAB + cls*4 + 0], r1 = ws[O_RTAB + cls*4 + 1];
  float r2 = ws[O_RTAB + cls*4 + 2], r3 = ws[O_RTAB + cls*4 + 3];
  const float* WC = ws + O_WC;
  const float* WE = ws + O_WE;
  for (int idx = threadIdx.x; idx < 512; idx += 256) {
    int c = idx >> 3, k = idx & 7;
    float a =       r0 * WC[0*512 + k*64 + c];
    a = fmaf(r1, WC[1*512 + k*64 + c], a);
    a = fmaf(r2, WC[2*512 + k*64 + c], a);
    a = fmaf(r3, WC[3*512 + k*64 + c], a);
    ws[O_CWC + cls*512 + idx] = a;
    float b =       r0 * WE[0*512 + c*8 + k];
    b = fmaf(r1, WE[1*512 + c*8 + k], b);
    b = fmaf(r2, WE[2*512 + c*8 + k], b);
    b = fmaf(r3, WE[3*512 + c*8 + k], b);
    ws[O_CWE + cls*512 + idx] = b;
  }
}

// ---- 4. encoder conv 3->64, 3x3 pad 1, over 128x128 -> feat (CHW f32) ----
__global__ __launch_bounds__(256) void k_enc(const float* __restrict__ ws, float* __restrict__ feat) {
  int px = blockIdx.x*256 + threadIdx.x;    // 0..16383
  int oc = blockIdx.y;                      // 0..63
  int x = px & 127, y = px >> 7;
  const float* I = ws + O_INP;
  const float* EW = ws + O_ENCW + oc*27;
  float acc = ws[O_ENCB + oc];
  #pragma unroll
  for (int ic = 0; ic < 3; ic++) {
    const float* Ic = I + ic*(128*128);
    #pragma unroll
    for (int dy = -1; dy <= 1; dy++) {
      int yy = y + dy; bool vy = (yy >= 0) && (yy < 128);
      #pragma unroll
      for (int dx = -1; dx <= 1; dx++) {
        int xx = x + dx;
        bool ok = vy && (xx >= 0) && (xx < 128);
        float t = ok ? Ic[yy*128 + xx] : 0.0f;
        acc = fmaf(EW[ic*9 + (dy+1)*3 + (dx+1)], t, acc);
      }
    }
  }
  feat[oc*(128*128) + px] = acc;
}

// ---- 5. fused main+tail: per-tile halo v in LDS, tail conv -> pred ----
__global__ __launch_bounds__(256) void k_maintail(const float* __restrict__ ws, float* __restrict__ pred) {
  __shared__ bf16 shv[64*324];   // [c][pos], 18x18 halo, 41472 B
  int blk = blockIdx.x;          // 0..1023
  int tx0 = (blk & 31) * TILE, ty0 = (blk >> 5) * TILE;
  int t = threadIdx.x;
  const float* F = ws + O_FEAT;

  for (int s = t; s < 324; s += 256) {
    // decode class-sorted halo position
    int cls = 0;
    #pragma unroll
    for (int i = 1; i < 16; i++) cls += (s >= PREF[i]) ? 1 : 0;
    int j = s - PREF[cls];
    int a = cls >> 2, bb = cls & 3;
    int nx = ((bb == 0) | (bb == 3)) ? 5 : 4;
    int jy = (nx == 4) ? (j >> 2) : ((j*13) >> 6);   // j/4 or j/5 (j<25)
    int jx = j - jy*nx;
    int py = ((a + 1) & 3) + 4*jy;
    int px = ((bb + 1) & 3) + 4*jx;
    int pos = py*18 + px;
    int gy = ty0 - 1 + py, gx = tx0 - 1 + px;
    if ((gy < 0) | (gy >= HS) | (gx < 0) | (gx >= WSZ)) {
      for (int c = 0; c < NC; c++) shv[c*324 + pos] = __float2bfloat16(0.0f);
      continue;
    }
    // verify: (gy&3)==a, (gx&3)==bb since ty0,tx0 are multiples of 16
    float off0 = ws[O_OFFTAB + cls*2 + 0];
    float off1 = ws[O_OFFTAB + cls*2 + 1];
    float gxf = (((float)gx + 0.5f)*0.25f - 0.5f)*(2.0f/127.0f) - 1.0f + off0*(2.0f/127.0f);
    float gyf = (((float)gy + 0.5f)*0.25f - 0.5f)*(2.0f/127.0f) - 1.0f + off1*(2.0f/127.0f);
    float sx = (gxf + 1.0f)*0.5f*127.0f;
    float sy = (gyf + 1.0f)*0.5f*127.0f;
    float x0f = floorf(sx), y0f = floorf(sy);
    float fx = sx - x0f, fy = sy - y0f;
    int ix0 = (int)x0f, iy0 = (int)y0f;
    int ix1 = ix0 + 1, iy1 = iy0 + 1;
    float wx0 = 1.0f - fx, wy0 = 1.0f - fy;
    float w00 = wy0*wx0, w01 = wy0*fx, w10 = fy*wx0, w11 = fy*fx;
    bool vx0 = (ix0 >= 0) & (ix0 < WW), vx1 = (ix1 >= 0) & (ix1 < WW);
    bool vy0 = (iy0 >= 0) & (iy0 < HH), vy1 = (iy1 >= 0) & (iy1 < HH);
    if (!(vy0 & vx0)) w00 = 0.0f;
    if (!(vy0 & vx1)) w01 = 0.0f;
    if (!(vy1 & vx0)) w10 = 0.0f;
    if (!(vy1 & vx1)) w11 = 0.0f;
    int cx0 = min(max(ix0, 0), WW-1), cx1 = min(max(ix1, 0), WW-1);
    int cy0 = min(max(iy0, 0), HH-1), cy1 = min(max(iy1, 0), HH-1);
    int b00 = cy0*WW + cx0, b01 = cy0*WW + cx1, b10 = cy1*WW + cx0, b11 = cy1*WW + cx1;

    const float* CWC = ws + O_CWC + cls*512;
    const float* CWE = ws + O_CWE + cls*512;
    float mid[8];
    #pragma unroll
    for (int k = 0; k < 8; k++) mid[k] = 0.0f;
    for (int c = 0; c < NC; c++) {
      const float* Fc = F + c*(HH*WW);
      float fc = w00*Fc[b00] + w01*Fc[b01] + w10*Fc[b10] + w11*Fc[b11];
      shv[c*324 + pos] = __float2bfloat16(fc);
      #pragma unroll
      for (int k = 0; k < 8; k++) mid[k] = fmaf(CWC[c*8 + k], fc, mid[k]);
    }
    for (int c = 0; c < NC; c++) {
      float fc = bf2f(shv[c*324 + pos]);
      float oc = 0.0f;
      #pragma unroll
      for (int k = 0; k < 8; k++) oc = fmaf(CWE[c*8 + k], mid[k], oc);
      shv[c*324 + pos] = __float2bfloat16(oc + fc);
    }
  }
  __syncthreads();

  // tail conv 64->3 over the 16x16 tile
  int tx = t & 15, ty = t >> 4;
  int gy = ty0 + ty, gx = tx0 + tx;
  int pc = (ty + 1)*18 + (tx + 1);
  const float* TW = ws + O_TW;   // [o][c][3][3]
  float a0 = ws[O_TB + 0], a1 = ws[O_TB + 1], a2 = ws[O_TB + 2];
  for (int c = 0; c < NC; c++) {
    const bf16* vc = shv + c*324;
    float t0 = bf2f(vc[pc - 19]), t1 = bf2f(vc[pc - 18]), t2 = bf2f(vc[pc - 17]);
    float t3 = bf2f(vc[pc - 1 ]), t4 = bf2f(vc[pc     ]), t5 = bf2f(vc[pc + 1 ]);
    float t6 = bf2f(vc[pc + 17]), t7 = bf2f(vc[pc + 18]), t8 = bf2f(vc[pc + 19]);
    const float* w0 = TW + (0*64 + c)*9;
    const float* w1 = TW + (1*64 + c)*9;
    const float* w2 = TW + (2*64 + c)*9;
    a0 = fmaf(w0[0],t0,a0); a0 = fmaf(w0[1],t1,a0); a0 = fmaf(w0[2],t2,a0);
    a0 = fmaf(w0[3],t3,a0); a0 = fmaf(w0[4],t4,a0); a0 = fmaf(w0[5],t5,a0);
    a0 = fmaf(w0[6],t6,a0); a0 = fmaf(w0[7],t7,a0); a0 = fmaf(w0[8],t8,a0);
    a1 = fmaf(w1[0],t0,a1); a1 = fmaf(w1[1],t1,a1); a1 = fmaf(w1[2],t2,a1);
    a1 = fmaf(w1[3],t3,a1); a1 = fmaf(w1[4],t4,a1); a1 = fmaf(w1[5],t5,a1);
    a1 = fmaf(w1[6],t6,a1); a1 = fmaf(w1[7],t7,a1); a1 = fmaf(w1[8],t8,a1);
    a2 = fmaf(w2[0],t0,a2); a2 = fmaf(w2[1],t1,a2); a2 = fmaf(w2[2],t2,a2);
    a2 = fmaf(w2[3],t3,a2); a2 = fmaf(w2[4],t4,a2); a2 = fmaf(w2[5],t5,a2);
    a2 = fmaf(w2[6],t6,a2); a2 = fmaf(w2[7],t7,a2); a2 = fmaf(w2[8],t8,a2);
  }
  int p = gy*WSZ + gx;
  pred[0*QN + p] = a0;
  pred[1*QN + p] = a1;
  pred[2*QN + p] = a2;
}

// ---- 6. query gather (dtype-flag aware for coord/cell/out) ----
__global__ __launch_bounds__(256) void k_gather(const void* __restrict__ coord, const void* __restrict__ cell,
                                                const float* __restrict__ ws, void* __restrict__ outp) {
  const float* pred = ws + O_PRED;
  bool f32m = ws[O_FLAG] > 0.5f;
  int q = blockIdx.x*256 + threadIdx.x;     // 0..262143
  float cy = rdin(coord, q*2 + 0, f32m);
  float cx = rdin(coord, q*2 + 1, f32m);
  float ly = rdin(cell, q*2 + 0, f32m);
  float lx = rdin(cell, q*2 + 1, f32m);
  float gyq = fminf(fmaxf(cy - ly*0.5f + 1e-6f, -1.0f + 1e-6f), 1.0f - 1e-6f);
  float gxq = fminf(fmaxf(cx - lx*0.5f + 1e-6f, -1.0f + 1e-6f), 1.0f - 1e-6f);
  int xi = (int)rintf((gxq + 1.0f)*0.5f*511.0f);   // round-half-even matches np.round
  int yi = (int)rintf((gyq + 1.0f)*0.5f*511.0f);
  xi = min(max(xi, 0), WSZ-1);
  yi = min(max(yi, 0), HS-1);
  int pp = yi*WSZ + xi;
  float v0 = pred[0*QN + pp], v1 = pred[1*QN + pp], v2 = pred[2*QN + pp];
  if (f32m) {
    float* o = (float*)outp;
    o[q*3 + 0] = v0; o[q*3 + 1] = v1; o[q*3 + 2] = v2;
  } else {
    bf16* o = (bf16*)outp;
    o[q*3 + 0] = __float2bfloat16(v0);
    o[q*3 + 1] = __float2bfloat16(v1);
    o[q*3 + 2] = __float2bfloat16(v2);
  }
}

extern "C" void kernel_launch(void* const* d_in, const int* in_sizes, int n_in,
                              void* d_out, int out_size, void* d_ws, size_t ws_size,
                              hipStream_t stream) {
  const void* inp   = d_in[0];
  const void* coord = d_in[1];
  const void* cell  = d_in[2];
  const void* encw  = d_in[3];
  const void* encb  = d_in[4];
  const void* w1    = d_in[5];
  const void* b1    = d_in[6];
  const void* w2    = d_in[7];
  const void* b2    = d_in[8];
  const void* rw    = d_in[9];
  const void* rb    = d_in[10];
  const void* ow    = d_in[11];
  const void* ob    = d_in[12];
  const void* tw    = d_in[13];
  const void* tb    = d_in[14];
  const void* wc    = d_in[15];
  const void* we    = d_in[16];

  float* wsf  = (float*)d_ws;
  float* feat = wsf + O_FEAT;
  float* pred = wsf + O_PRED;

  k_sniff<<<1, 64, 0, stream>>>(inp, wsf);
  k_convert<<<192, 256, 0, stream>>>(inp, encw, encb, w1, b1, w2, b2, rw, rb, ow, ob, tw, tb, wc, we, wsf);
  k_class<<<16, 64, 0, stream>>>(wsf);
  k_combine<<<16, 256, 0, stream>>>(wsf);
  k_enc<<<dim3(64, 64), 256, 0, stream>>>(wsf, feat);
  k_maintail<<<1024, 256, 0, stream>>>(wsf, pred);
  k_gather<<<1024, 256, 0, stream>>>(coord, cell, wsf, d_out);
}

// Round 3
// 262.013 us; speedup vs baseline: 1.0729x; 1.0729x over previous
//
#include <hip/hip_runtime.h>
#include <hip/hip_bf16.h>

typedef __hip_bfloat16 bf16;

__device__ __forceinline__ float bf2f(bf16 h) { return __bfloat162float(h); }
__device__ __forceinline__ bf16 us2bf(unsigned short u) {
  union { unsigned short s; bf16 h; } v; v.s = u; return v.h;
}
__device__ __forceinline__ unsigned int pk2(float a, float b) {
  union { bf16 h; unsigned short u; } ua, ub;
  ua.h = __float2bfloat16(a); ub.h = __float2bfloat16(b);
  return ((unsigned int)ub.u << 16) | (unsigned int)ua.u;
}
__device__ __forceinline__ float asf(unsigned int u) {
  union { unsigned int u; float f; } v; v.u = u; return v.f;
}

#define HH 128
#define WW 128
#define HS 512
#define WSZ 512
#define NC 64
#define QN (HS*WSZ)

// ---- ws float-offset layout (total ~7.67 MB, same envelope as passing round) ----
#define O_INP    0        // 49152
#define O_ENCW   49152    // 1728
#define O_ENCB   50880    // 64
#define O_W1     50944    // 256
#define O_B1     51200    // 64
#define O_W2     51264    // 4096
#define O_B2     55360    // 64
#define O_RW     55424    // 256
#define O_RB     55680    // 4
#define O_OW     55684    // 128
#define O_OB     55812    // 2
#define O_TW     55814    // 1728
#define O_TB     57542    // 3
#define O_WC     57545    // 2048
#define O_WE     59593    // 2048  (end 61641)
#define O_OFFTAB 61696    // 32
#define O_RTAB   61728    // 64
#define O_FLAG   61792    // 1
#define O_CWC    61824    // 16*512 (layout [cls][k][c])
#define O_CWE    70016    // 16*512 (layout [cls][c][k])
#define O_TWP    78208    // 1728   (layout [o][j][c], c-contig)
#define O_FEAT   81920    // 16384*64 f32 HWC  (end 1130496)
#define O_PRED   1130496  // 262144*3 f32 HWC (end 1916928)

// class-sorted halo decode prefix (18x18 halo, classes by ((p+3)&3))
__constant__ int PREF[16] = {0,25,45,65,90,110,126,142,162,182,198,214,234,259,279,299};

__device__ __forceinline__ float rdin(const void* p, int i, bool f32m) {
  return f32m ? ((const float*)p)[i] : bf2f(((const bf16*)p)[i]);
}

// ---- 0. dtype sniff ----
__global__ void k_sniff(const void* __restrict__ inp, float* __restrict__ ws) {
  int o = threadIdx.x;
  unsigned short u = ((const unsigned short*)inp)[2*o];
  float v = bf2f(us2bf(u));
  bool bf_ok = (v == v) && (fabsf(v) < 64.0f);
  unsigned long long m = __ballot(bf_ok);
  if (o == 0) ws[O_FLAG] = (__popcll(m) >= 48) ? 0.0f : 1.0f;
}

// ---- 1. convert inputs/weights to f32 ----
__global__ __launch_bounds__(256) void k_convert(
    const void* __restrict__ inp, const void* __restrict__ encw, const void* __restrict__ encb,
    const void* __restrict__ w1, const void* __restrict__ b1,
    const void* __restrict__ w2, const void* __restrict__ b2,
    const void* __restrict__ rw, const void* __restrict__ rb,
    const void* __restrict__ ow, const void* __restrict__ ob,
    const void* __restrict__ tw, const void* __restrict__ tb,
    const void* __restrict__ wc, const void* __restrict__ we,
    float* __restrict__ ws) {
  bool f32m = ws[O_FLAG] > 0.5f;
  int i = blockIdx.x*256 + threadIdx.x;
  if (i < 49152) ws[O_INP + i] = rdin(inp, i, f32m);
  if (i < 1728) { ws[O_ENCW + i] = rdin(encw, i, f32m); ws[O_TW + i] = rdin(tw, i, f32m); }
  if (i < 64)   { ws[O_ENCB+i] = rdin(encb,i,f32m); ws[O_B1+i] = rdin(b1,i,f32m); ws[O_B2+i] = rdin(b2,i,f32m); }
  if (i < 256)  { ws[O_W1+i] = rdin(w1,i,f32m); ws[O_RW+i] = rdin(rw,i,f32m); }
  if (i < 4096) ws[O_W2+i] = rdin(w2,i,f32m);
  if (i < 4)    ws[O_RB+i] = rdin(rb,i,f32m);
  if (i < 128)  ws[O_OW+i] = rdin(ow,i,f32m);
  if (i < 2)    ws[O_OB+i] = rdin(ob,i,f32m);
  if (i < 3)    ws[O_TB+i] = rdin(tb,i,f32m);
  if (i < 2048) { ws[O_WC+i] = rdin(wc,i,f32m); ws[O_WE+i] = rdin(we,i,f32m); }
}

// ---- 2. per-class MLP -> off, r; fold r into combined expert weights; transpose tail weights ----
__global__ __launch_bounds__(64) void k_classcombine(float* __restrict__ ws) {
  __shared__ float sh1[64];
  __shared__ float sh2[64];
  __shared__ float shr[4];
  int cls = blockIdx.x;
  int o = threadIdx.x;
  float m = (float)(cls >> 2), n = (float)(cls & 3);
  float ch = (m + 0.5f)*0.25f - 0.5f;
  float cw = (n + 0.5f)*0.25f - 0.5f;
  const float* W1 = ws + O_W1; const float* B1 = ws + O_B1;
  const float* W2 = ws + O_W2; const float* B2 = ws + O_B2;
  float s = W1[o*4+0]*0.25f + W1[o*4+1]*0.25f + W1[o*4+2]*ch + W1[o*4+3]*cw + B1[o];
  sh1[o] = fmaxf(s, 0.0f);
  __syncthreads();
  float s2 = B2[o];
  for (int i = 0; i < 64; i++) s2 = fmaf(W2[o*64+i], sh1[i], s2);
  sh2[o] = fmaxf(s2, 0.0f);
  __syncthreads();
  if (o < 2) {
    const float* OW = ws + O_OW;
    float a = ws[O_OB + o];
    for (int i = 0; i < 64; i++) a = fmaf(OW[o*64+i], sh2[i], a);
    ws[O_OFFTAB + cls*2 + o] = a;
  } else if (o < 6) {
    int e = o - 2;
    const float* RW = ws + O_RW;
    float a = ws[O_RB + e];
    for (int i = 0; i < 64; i++) a = fmaf(RW[e*64+i], sh2[i], a);
    shr[e] = 1.0f / (1.0f + expf(-a));
    ws[O_RTAB + cls*4 + e] = shr[e];
  }
  __syncthreads();
  float r0 = shr[0], r1 = shr[1], r2 = shr[2], r3 = shr[3];
  const float* WC = ws + O_WC;
  const float* WE = ws + O_WE;
  for (int idx = o; idx < 512; idx += 64) {
    // cwc2[cls][k][c], idx = k*64+c; source WC[e][k][c] flat (e*8+k)*64+c
    float a =       r0 * WC[0*512 + idx];
    a = fmaf(r1, WC[1*512 + idx], a);
    a = fmaf(r2, WC[2*512 + idx], a);
    a = fmaf(r3, WC[3*512 + idx], a);
    ws[O_CWC + cls*512 + idx] = a;
    // cwe[cls][c][k], idx = c*8+k; source WE[e][c][k] flat e*512 + c*8+k
    float b =       r0 * WE[0*512 + idx];
    b = fmaf(r1, WE[1*512 + idx], b);
    b = fmaf(r2, WE[2*512 + idx], b);
    b = fmaf(r3, WE[3*512 + idx], b);
    ws[O_CWE + cls*512 + idx] = b;
  }
  if (cls == 0) {
    // twp[(oo*9+jj)*64 + c] = tw[(oo*64+c)*9 + jj]
    for (int idx = o; idx < 1728; idx += 64) {
      int oo = idx / 576;
      int rem = idx - oo*576;
      int jj = rem >> 6;
      int c = rem & 63;
      ws[O_TWP + idx] = ws[O_TW + (oo*64 + c)*9 + jj];
    }
  }
}

// ---- 3. encoder conv 3->64 -> feat HWC f32 ----
__global__ __launch_bounds__(256) void k_enc(const float* __restrict__ ws, float* __restrict__ feat) {
  int px = blockIdx.x*256 + threadIdx.x;    // 0..16383
  int x = px & 127, y = px >> 7;
  const float* I = ws + O_INP;
  float tp[27];
  #pragma unroll
  for (int ic = 0; ic < 3; ic++) {
    #pragma unroll
    for (int dy = 0; dy < 3; dy++) {
      int yy = y + dy - 1;
      #pragma unroll
      for (int dx = 0; dx < 3; dx++) {
        int xx = x + dx - 1;
        bool ok = (yy >= 0) & (yy < 128) & (xx >= 0) & (xx < 128);
        tp[ic*9 + dy*3 + dx] = ok ? I[ic*16384 + yy*128 + xx] : 0.0f;
      }
    }
  }
  const float* EW = ws + O_ENCW;
  float4* out = (float4*)(feat + (size_t)px*64);
  for (int og = 0; og < 16; og++) {
    float a[4];
    #pragma unroll
    for (int oo = 0; oo < 4; oo++) {
      float acc = ws[O_ENCB + og*4 + oo];
      #pragma unroll
      for (int kk = 0; kk < 27; kk++) acc = fmaf(EW[(og*4 + oo)*27 + kk], tp[kk], acc);
      a[oo] = acc;
    }
    out[og] = make_float4(a[0], a[1], a[2], a[3]);
  }
}

// ---- 4. fused main+tail ----
__global__ __launch_bounds__(256, 3) void k_maintail(const float* __restrict__ ws, float* __restrict__ pred) {
  __shared__ unsigned int shd[32*325];     // [c_pair][slot], 41600 B
  __shared__ unsigned short sof[324];      // pos -> slot
  int blk = blockIdx.x;
  int tx0 = (blk & 31) * 16, ty0 = (blk >> 5) * 16;
  int t = threadIdx.x;
  const float4* Fv = (const float4*)(ws + O_FEAT);

  for (int s = t; s < 324; s += 256) {
    int cls = 0;
    #pragma unroll
    for (int i = 1; i < 16; i++) cls += (s >= PREF[i]) ? 1 : 0;
    int j = s - PREF[cls];
    int a = cls >> 2, bb = cls & 3;
    int nx = ((bb == 0) | (bb == 3)) ? 5 : 4;
    int jy = (nx == 4) ? (j >> 2) : ((j*13) >> 6);
    int jx = j - jy*nx;
    int py = ((a + 1) & 3) + 4*jy;
    int px = ((bb + 1) & 3) + 4*jx;
    int pos = py*18 + px;
    sof[pos] = (unsigned short)s;
    int gy = ty0 - 1 + py, gx = tx0 - 1 + px;
    if ((gy < 0) | (gy >= HS) | (gx < 0) | (gx >= WSZ)) {
      #pragma unroll
      for (int cp = 0; cp < 32; cp++) shd[cp*325 + s] = 0u;
      continue;
    }
    float off0 = ws[O_OFFTAB + cls*2 + 0];
    float off1 = ws[O_OFFTAB + cls*2 + 1];
    float gxf = (((float)gx + 0.5f)*0.25f - 0.5f)*(2.0f/127.0f) - 1.0f + off0*(2.0f/127.0f);
    float gyf = (((float)gy + 0.5f)*0.25f - 0.5f)*(2.0f/127.0f) - 1.0f + off1*(2.0f/127.0f);
    float sx = (gxf + 1.0f)*0.5f*127.0f;
    float sy = (gyf + 1.0f)*0.5f*127.0f;
    float x0f = floorf(sx), y0f = floorf(sy);
    float fx = sx - x0f, fy = sy - y0f;
    int ix0 = (int)x0f, iy0 = (int)y0f;
    int ix1 = ix0 + 1, iy1 = iy0 + 1;
    float wx0 = 1.0f - fx, wy0 = 1.0f - fy;
    float w00 = wy0*wx0, w01 = wy0*fx, w10 = fy*wx0, w11 = fy*fx;
    bool vx0 = (ix0 >= 0) & (ix0 < WW), vx1 = (ix1 >= 0) & (ix1 < WW);
    bool vy0 = (iy0 >= 0) & (iy0 < HH), vy1 = (iy1 >= 0) & (iy1 < HH);
    if (!(vy0 & vx0)) w00 = 0.0f;
    if (!(vy0 & vx1)) w01 = 0.0f;
    if (!(vy1 & vx0)) w10 = 0.0f;
    if (!(vy1 & vx1)) w11 = 0.0f;
    int cx0 = min(max(ix0, 0), WW-1), cx1 = min(max(ix1, 0), WW-1);
    int cy0 = min(max(iy0, 0), HH-1), cy1 = min(max(iy1, 0), HH-1);
    int b00 = (cy0*WW + cx0)*16, b01 = (cy0*WW + cx1)*16;
    int b10 = (cy1*WW + cx0)*16, b11 = (cy1*WW + cx1)*16;

    // bilinear, fc kept in registers (HWC float4 taps)
    float4 fc4[16];
    #pragma unroll
    for (int cg = 0; cg < 16; cg++) {
      float4 t00 = Fv[b00 + cg], t01 = Fv[b01 + cg];
      float4 t10 = Fv[b10 + cg], t11 = Fv[b11 + cg];
      float4 f;
      f.x = fmaf(w00,t00.x, fmaf(w01,t01.x, fmaf(w10,t10.x, w11*t11.x)));
      f.y = fmaf(w00,t00.y, fmaf(w01,t01.y, fmaf(w10,t10.y, w11*t11.y)));
      f.z = fmaf(w00,t00.z, fmaf(w01,t01.z, fmaf(w10,t10.z, w11*t11.z)));
      f.w = fmaf(w00,t00.w, fmaf(w01,t01.w, fmaf(w10,t10.w, w11*t11.w)));
      fc4[cg] = f;
    }
    // phase 1: mid[k] = sum_c cwc2[k][c]*fc[c]
    const float4* CWv = (const float4*)(ws + O_CWC + cls*512);
    float mid[8];
    #pragma unroll
    for (int k = 0; k < 8; k++) {
      float mm = 0.0f;
      #pragma unroll
      for (int cg = 0; cg < 16; cg++) {
        float4 w = CWv[k*16 + cg];
        mm = fmaf(w.x, fc4[cg].x, fmaf(w.y, fc4[cg].y, fmaf(w.z, fc4[cg].z, fmaf(w.w, fc4[cg].w, mm))));
      }
      mid[k] = mm;
    }
    // phase 2: out[c] = sum_k cwe[c][k]*mid[k]; v = out + fc -> packed bf16 pairs
    const float4* WEv = (const float4*)(ws + O_CWE + cls*512);
    #pragma unroll
    for (int cg = 0; cg < 16; cg++) {
      float vv[4];
      #define PH2(cc, fcomp) { \
        int c_ = cg*4 + cc; \
        float4 wa = WEv[c_*2], wb = WEv[c_*2 + 1]; \
        float o_ = fmaf(wa.x,mid[0], fmaf(wa.y,mid[1], fmaf(wa.z,mid[2], wa.w*mid[3]))); \
        o_ = fmaf(wb.x,mid[4], fmaf(wb.y,mid[5], fmaf(wb.z,mid[6], fmaf(wb.w,mid[7], o_)))); \
        vv[cc] = o_ + fcomp; }
      PH2(0, fc4[cg].x)
      PH2(1, fc4[cg].y)
      PH2(2, fc4[cg].z)
      PH2(3, fc4[cg].w)
      #undef PH2
      shd[(2*cg)*325 + s]   = pk2(vv[0], vv[1]);
      shd[(2*cg+1)*325 + s] = pk2(vv[2], vv[3]);
    }
  }
  __syncthreads();

  // tail conv 64->3 over 16x16 tile from LDS
  int tx = t & 15, ty = t >> 4;
  int slots[9];
  #pragma unroll
  for (int dy = 0; dy < 3; dy++)
    #pragma unroll
    for (int dx = 0; dx < 3; dx++)
      slots[dy*3 + dx] = sof[(ty + dy)*18 + (tx + dx)];
  const float* TWP = ws + O_TWP;
  float a0 = ws[O_TB + 0], a1 = ws[O_TB + 1], a2 = ws[O_TB + 2];
  for (int cp = 0; cp < 32; cp++) {
    #pragma unroll
    for (int j = 0; j < 9; j++) {
      unsigned int d = shd[cp*325 + slots[j]];
      float lo = asf(d << 16);
      float hi = asf(d & 0xffff0000u);
      float wl0 = TWP[(0*9 + j)*64 + 2*cp], wh0 = TWP[(0*9 + j)*64 + 2*cp + 1];
      float wl1 = TWP[(1*9 + j)*64 + 2*cp], wh1 = TWP[(1*9 + j)*64 + 2*cp + 1];
      float wl2 = TWP[(2*9 + j)*64 + 2*cp], wh2 = TWP[(2*9 + j)*64 + 2*cp + 1];
      a0 = fmaf(wl0, lo, fmaf(wh0, hi, a0));
      a1 = fmaf(wl1, lo, fmaf(wh1, hi, a1));
      a2 = fmaf(wl2, lo, fmaf(wh2, hi, a2));
    }
  }
  int p = (ty0 + ty)*WSZ + (tx0 + tx);
  pred[p*3 + 0] = a0;
  pred[p*3 + 1] = a1;
  pred[p*3 + 2] = a2;
}

// ---- 5. query gather ----
__global__ __launch_bounds__(256) void k_gather(const void* __restrict__ coord, const void* __restrict__ cell,
                                                const float* __restrict__ ws, void* __restrict__ outp) {
  const float* pred = ws + O_PRED;
  bool f32m = ws[O_FLAG] > 0.5f;
  int q = blockIdx.x*256 + threadIdx.x;
  float cy = rdin(coord, q*2 + 0, f32m);
  float cx = rdin(coord, q*2 + 1, f32m);
  float ly = rdin(cell, q*2 + 0, f32m);
  float lx = rdin(cell, q*2 + 1, f32m);
  float gyq = fminf(fmaxf(cy - ly*0.5f + 1e-6f, -1.0f + 1e-6f), 1.0f - 1e-6f);
  float gxq = fminf(fmaxf(cx - lx*0.5f + 1e-6f, -1.0f + 1e-6f), 1.0f - 1e-6f);
  int xi = (int)rintf((gxq + 1.0f)*0.5f*511.0f);
  int yi = (int)rintf((gyq + 1.0f)*0.5f*511.0f);
  xi = min(max(xi, 0), WSZ-1);
  yi = min(max(yi, 0), HS-1);
  int pp = yi*WSZ + xi;
  float v0 = pred[pp*3 + 0], v1 = pred[pp*3 + 1], v2 = pred[pp*3 + 2];
  if (f32m) {
    float* o = (float*)outp;
    o[q*3 + 0] = v0; o[q*3 + 1] = v1; o[q*3 + 2] = v2;
  } else {
    bf16* o = (bf16*)outp;
    o[q*3 + 0] = __float2bfloat16(v0);
    o[q*3 + 1] = __float2bfloat16(v1);
    o[q*3 + 2] = __float2bfloat16(v2);
  }
}

extern "C" void kernel_launch(void* const* d_in, const int* in_sizes, int n_in,
                              void* d_out, int out_size, void* d_ws, size_t ws_size,
                              hipStream_t stream) {
  const void* inp   = d_in[0];
  const void* coord = d_in[1];
  const void* cell  = d_in[2];
  const void* encw  = d_in[3];
  const void* encb  = d_in[4];
  const void* w1    = d_in[5];
  const void* b1    = d_in[6];
  const void* w2    = d_in[7];
  const void* b2    = d_in[8];
  const void* rw    = d_in[9];
  const void* rb    = d_in[10];
  const void* ow    = d_in[11];
  const void* ob    = d_in[12];
  const void* tw    = d_in[13];
  const void* tb    = d_in[14];
  const void* wc    = d_in[15];
  const void* we    = d_in[16];

  float* wsf  = (float*)d_ws;
  float* feat = wsf + O_FEAT;
  float* pred = wsf + O_PRED;

  k_sniff<<<1, 64, 0, stream>>>(inp, wsf);
  k_convert<<<192, 256, 0, stream>>>(inp, encw, encb, w1, b1, w2, b2, rw, rb, ow, ob, tw, tb, wc, we, wsf);
  k_classcombine<<<16, 64, 0, stream>>>(wsf);
  k_enc<<<64, 256, 0, stream>>>(wsf, feat);
  k_maintail<<<1024, 256, 0, stream>>>(wsf, pred);
  k_gather<<<1024, 256, 0, stream>>>(coord, cell, wsf, d_out);
}